// Round 1
// baseline (143.076 us; speedup 1.0000x reference)
//
#include <hip/hip_runtime.h>

#define BB 1024
#define DD 512
#define OO 256

// ---------------------------------------------------------------------------
// k0: transpose x (B,D) -> xT (D,B) so per-column gathers are coalesced in b
// ---------------------------------------------------------------------------
__global__ __launch_bounds__(256) void k0_transpose(const float* __restrict__ x,
                                                    float* __restrict__ xT) {
  __shared__ float tile[32][33];
  int b0 = blockIdx.x * 32;  // b tile base
  int d0 = blockIdx.y * 32;  // d tile base
  int tx = threadIdx.x;      // 0..31
  int ty = threadIdx.y;      // 0..7
  for (int i = 0; i < 32; i += 8)
    tile[ty + i][tx] = x[(size_t)(b0 + ty + i) * DD + d0 + tx];
  __syncthreads();
  for (int i = 0; i < 32; i += 8)
    xT[(size_t)(d0 + ty + i) * BB + b0 + tx] = tile[tx][ty + i];
}

// ---------------------------------------------------------------------------
// k1: f64 sums  Sx[d] = sum_b (1-x[b,d]);  Sw[o] = sum_d (1-w[d,o]);
//               Wtot[o] = sum_d w[d,o]
// ---------------------------------------------------------------------------
__global__ __launch_bounds__(256) void k1_sums(const float* __restrict__ x,
                                               const float* __restrict__ w,
                                               double* __restrict__ Sx,
                                               double* __restrict__ Sw,
                                               double* __restrict__ Wtot) {
  int gid = blockIdx.x * 256 + threadIdx.x;
  if (gid < DD) {
    double s = 0.0;
    for (int b = 0; b < BB; ++b) s += 1.0 - (double)x[(size_t)b * DD + gid];
    Sx[gid] = s;
  } else {
    int o = gid - DD;
    if (o < OO) {
      double s = 0.0, wt = 0.0;
      for (int d = 0; d < DD; ++d) {
        double wv = (double)w[(size_t)d * OO + o];
        s += 1.0 - wv;
        wt += wv;
      }
      Sw[o] = s;
      Wtot[o] = wt;
    }
  }
}

// ---------------------------------------------------------------------------
// k2: rel_x[d,o] = 1 - (B - sum_b max(x[b,d],t[b,o])) / Sx[d]   (f64 acc)
//     one block = 2 d's x all 256 o's; 256 blocks
// ---------------------------------------------------------------------------
__global__ __launch_bounds__(256) void k2_relx(const float* __restrict__ xT,
                                               const float* __restrict__ t,
                                               const double* __restrict__ Sx,
                                               double* __restrict__ relx) {
  int o = threadIdx.x;
  int d0 = blockIdx.x * 2;
  const float* x0 = xT + (size_t)d0 * BB;
  const float* x1 = xT + (size_t)(d0 + 1) * BB;
  double a0 = 0.0, a1 = 0.0;
  for (int b = 0; b < BB; b += 4) {
    float tv0 = t[(size_t)(b + 0) * OO + o];
    float tv1 = t[(size_t)(b + 1) * OO + o];
    float tv2 = t[(size_t)(b + 2) * OO + o];
    float tv3 = t[(size_t)(b + 3) * OO + o];
    float p00 = x0[b + 0], p01 = x0[b + 1], p02 = x0[b + 2], p03 = x0[b + 3];
    float p10 = x1[b + 0], p11 = x1[b + 1], p12 = x1[b + 2], p13 = x1[b + 3];
    // pair sums of two exact f32 values are exact in f64
    a0 += (double)fmaxf(p00, tv0) + (double)fmaxf(p01, tv1);
    a0 += (double)fmaxf(p02, tv2) + (double)fmaxf(p03, tv3);
    a1 += (double)fmaxf(p10, tv0) + (double)fmaxf(p11, tv1);
    a1 += (double)fmaxf(p12, tv2) + (double)fmaxf(p13, tv3);
  }
  relx[(size_t)(d0 + 0) * OO + o] = 1.0 - ((double)BB - a0) / Sx[d0 + 0];
  relx[(size_t)(d0 + 1) * OO + o] = 1.0 - ((double)BB - a1) / Sx[d0 + 1];
}

// ---------------------------------------------------------------------------
// k3: per-o preprocessing. Bitonic sort (lexicographic (key, idx) -> unique
// total order == stable sort) of (a) w column, (b) rel_x column; then f64
// inclusive prefix sum of sorted w and prefix-min of original indices.
// ---------------------------------------------------------------------------
__device__ void bitonic512(double* key, int* idx, int tid) {
  for (int k = 2; k <= 512; k <<= 1) {
    for (int j = k >> 1; j > 0; j >>= 1) {
      __syncthreads();
      for (int i = tid; i < 512; i += 256) {
        int p = i ^ j;
        if (p > i) {
          double ka = key[i], kb = key[p];
          int ia = idx[i], ib = idx[p];
          bool up = ((i & k) == 0);
          bool agtb = (ka > kb) || (ka == kb && ia > ib);
          if (up == agtb) {
            key[i] = kb; key[p] = ka;
            idx[i] = ib; idx[p] = ia;
          }
        }
      }
    }
  }
  __syncthreads();
}

__global__ __launch_bounds__(256) void k3_sort(const float* __restrict__ w,
                                               const double* __restrict__ relx,
                                               double* __restrict__ wpre,
                                               double* __restrict__ rxv,
                                               float* __restrict__ wsrt,
                                               int* __restrict__ pm,
                                               int* __restrict__ rxi) {
  int o = blockIdx.x;
  int tid = threadIdx.x;
  __shared__ double key[512];
  __shared__ int idx[512];
  __shared__ double scn[512];
  __shared__ int mn[512];

  // ---- w column ----
  for (int i = tid; i < 512; i += 256) {
    key[i] = (double)w[(size_t)i * OO + o];
    idx[i] = i;
  }
  bitonic512(key, idx, tid);
  for (int i = tid; i < 512; i += 256) {
    scn[i] = key[i];
    mn[i] = idx[i];
  }
  // Hillis-Steele inclusive scan: sum(key) and min(idx)
  for (int off = 1; off < 512; off <<= 1) {
    double v0, v1; int m0, m1;
    __syncthreads();
    {
      int i0 = tid, i1 = tid + 256;
      v0 = (i0 >= off) ? scn[i0 - off] : 0.0;
      v1 = (i1 >= off) ? scn[i1 - off] : 0.0;
      m0 = (i0 >= off) ? mn[i0 - off] : 0x7fffffff;
      m1 = (i1 >= off) ? mn[i1 - off] : 0x7fffffff;
    }
    __syncthreads();
    {
      int i0 = tid, i1 = tid + 256;
      scn[i0] += v0; scn[i1] += v1;
      mn[i0] = mn[i0] < m0 ? mn[i0] : m0;
      mn[i1] = mn[i1] < m1 ? mn[i1] : m1;
    }
  }
  __syncthreads();
  for (int i = tid; i < 512; i += 256) {
    wsrt[(size_t)o * 512 + i] = (float)key[i];
    wpre[(size_t)o * 512 + i] = scn[i];
    pm[(size_t)o * 512 + i] = mn[i];
  }
  __syncthreads();

  // ---- rel_x column ----
  for (int i = tid; i < 512; i += 256) {
    key[i] = relx[(size_t)i * OO + o];
    idx[i] = i;
  }
  bitonic512(key, idx, tid);
  for (int i = tid; i < 512; i += 256) {
    rxv[(size_t)o * 512 + i] = key[i];
    rxi[(size_t)o * 512 + i] = idx[i];
  }
}

// ---------------------------------------------------------------------------
// k4: per (b,o): rel_w via binary search + prefix sums; ind_w via binary
// search + prefix-min; ind_x via early-exit scan in ascending rel_x order.
// block = one o x 256 b's; grid = (O, B/256)
// ---------------------------------------------------------------------------
__global__ __launch_bounds__(256) void k4_final(
    const float* __restrict__ xT, const float* __restrict__ w,
    const float* __restrict__ t, const double* __restrict__ Sw,
    const double* __restrict__ Wtot, const double* __restrict__ wpre,
    const double* __restrict__ rxv, const float* __restrict__ wsrt,
    const int* __restrict__ pm, const int* __restrict__ rxi,
    float* __restrict__ out) {
  int o = blockIdx.x;
  int tid = threadIdx.x;
  int b = blockIdx.y * 256 + tid;

  __shared__ float wsr_l[512];
  __shared__ double wpre_l[513];
  __shared__ double rxv_l[512];
  __shared__ int pm_l[512];
  __shared__ int rxi_l[512];

  for (int i = tid; i < 512; i += 256) {
    wsr_l[i] = wsrt[(size_t)o * 512 + i];
    wpre_l[i + 1] = wpre[(size_t)o * 512 + i];
    rxv_l[i] = rxv[(size_t)o * 512 + i];
    pm_l[i] = pm[(size_t)o * 512 + i];
    rxi_l[i] = rxi[(size_t)o * 512 + i];
  }
  if (tid == 0) wpre_l[0] = 0.0;
  __syncthreads();

  float c = t[(size_t)b * OO + o];

  // k = #{d : w[d,o] <= c}   (exact fp32 compare == f64 compare of exact vals)
  int lo = 0, hi = 512;
  while (lo < hi) {
    int mid = (lo + hi) >> 1;
    if (wsr_l[mid] <= c) lo = mid + 1; else hi = mid;
  }
  int k = lo;
  double smax = (Wtot[o] - wpre_l[k]) + (double)c * (double)k;
  double relw = 1.0 - ((double)DD - smax) / Sw[o];

  // k2 = #{d : (double)w[d,o] <= relw}
  lo = 0; hi = 512;
  while (lo < hi) {
    int mid = (lo + hi) >> 1;
    if ((double)wsr_l[mid] <= relw) lo = mid + 1; else hi = mid;
  }
  int iw = pm_l[(lo > 0) ? (lo - 1) : 0];

  // ind_x: argmin_d max(x[b,d], rel_x[d,o]), first-index tie-break.
  // Scan ascending sorted rel_x; stop when r_j > best (v_j >= r_j > best).
  double best = 1e300;
  int bix = 0x7fffffff;
  float xpf[8];
  int dpf[8];
  double rpf[8];
#pragma unroll
  for (int j = 0; j < 8; ++j) {
    dpf[j] = rxi_l[j];
    rpf[j] = rxv_l[j];
    xpf[j] = xT[(size_t)dpf[j] * BB + b];
  }
  bool done = false;
#pragma unroll
  for (int j = 0; j < 8; ++j) {
    if (!done) {
      if (rpf[j] > best) {
        done = true;
      } else {
        double v = fmax((double)xpf[j], rpf[j]);
        if (v < best || (v == best && dpf[j] < bix)) { best = v; bix = dpf[j]; }
      }
    }
  }
  if (!done) {
    for (int j = 8; j < 512; ++j) {
      double rj = rxv_l[j];
      if (rj > best) break;
      int dj = rxi_l[j];
      double v = fmax((double)xT[(size_t)dj * BB + b], rj);
      if (v < best || (v == best && dj < bix)) { best = v; bix = dj; }
    }
  }

  float ox = fmaxf(xT[(size_t)bix * BB + b], w[(size_t)bix * OO + o]);
  float ow = fmaxf(xT[(size_t)iw * BB + b], w[(size_t)iw * OO + o]);
  out[(size_t)b * OO + o] = ox;
  out[(size_t)BB * OO + (size_t)b * OO + o] = ow;
}

// ---------------------------------------------------------------------------
extern "C" void kernel_launch(void* const* d_in, const int* in_sizes, int n_in,
                              void* d_out, int out_size, void* d_ws,
                              size_t ws_size, hipStream_t stream) {
  const float* x = (const float*)d_in[0];  // (B,D)
  const float* w = (const float*)d_in[1];  // (D,O)
  const float* t = (const float*)d_in[2];  // (B,O)
  float* out = (float*)d_out;              // 2 * B*O fp32
  char* ws = (char*)d_ws;

  size_t off = 0;
  double* relx = (double*)(ws + off); off += (size_t)DD * OO * 8;   // 1 MB
  double* Sx   = (double*)(ws + off); off += (size_t)DD * 8;
  double* Sw   = (double*)(ws + off); off += (size_t)OO * 8;
  double* Wtot = (double*)(ws + off); off += (size_t)OO * 8;
  double* wpre = (double*)(ws + off); off += (size_t)OO * DD * 8;   // 1 MB
  double* rxv  = (double*)(ws + off); off += (size_t)OO * DD * 8;   // 1 MB
  float* wsrt  = (float*)(ws + off);  off += (size_t)OO * DD * 4;   // 0.5 MB
  int* pm      = (int*)(ws + off);    off += (size_t)OO * DD * 4;   // 0.5 MB
  int* rxi     = (int*)(ws + off);    off += (size_t)OO * DD * 4;   // 0.5 MB
  float* xT    = (float*)(ws + off);  off += (size_t)BB * DD * 4;   // 2 MB

  k0_transpose<<<dim3(BB / 32, DD / 32), dim3(32, 8), 0, stream>>>(x, xT);
  k1_sums<<<3, 256, 0, stream>>>(x, w, Sx, Sw, Wtot);
  k2_relx<<<DD / 2, 256, 0, stream>>>(xT, t, Sx, relx);
  k3_sort<<<OO, 256, 0, stream>>>(w, relx, wpre, rxv, wsrt, pm, rxi);
  k4_final<<<dim3(OO, BB / 256), 256, 0, stream>>>(xT, w, t, Sw, Wtot, wpre,
                                                   rxv, wsrt, pm, rxi, out);
}

// Round 2
// 82.067 us; speedup vs baseline: 1.7434x; 1.7434x over previous
//
#include <hip/hip_runtime.h>

#define BB 1024
#define DD 512
#define OO 256

#define D_TILE 4
#define B_SPLIT 8
#define B_TILE (BB / B_SPLIT)  // 128

// ---------------------------------------------------------------------------
// k0: transpose x (B,D) -> xT (D,B) so per-column gathers are coalesced in b
// ---------------------------------------------------------------------------
__global__ __launch_bounds__(256) void k0_transpose(const float* __restrict__ x,
                                                    float* __restrict__ xT) {
  __shared__ float tile[32][33];
  int b0 = blockIdx.x * 32;
  int d0 = blockIdx.y * 32;
  int tx = threadIdx.x;
  int ty = threadIdx.y;
  for (int i = 0; i < 32; i += 8)
    tile[ty + i][tx] = x[(size_t)(b0 + ty + i) * DD + d0 + tx];
  __syncthreads();
  for (int i = 0; i < 32; i += 8)
    xT[(size_t)(d0 + ty + i) * BB + b0 + tx] = tile[tx][ty + i];
}

// ---------------------------------------------------------------------------
// k1: one block per column. bid<DD: Sx[d]=sum_b(1-xT[d,b]) (coalesced).
//     bid>=DD: o=bid-DD: Sw[o]=sum_d(1-w[d,o]), Wtot[o]=sum_d w[d,o]
// ---------------------------------------------------------------------------
__global__ __launch_bounds__(256) void k1_sums(const float* __restrict__ xT,
                                               const float* __restrict__ w,
                                               double* __restrict__ Sx,
                                               double* __restrict__ Sw,
                                               double* __restrict__ Wtot) {
  __shared__ double red[256];
  int bid = blockIdx.x;
  int tid = threadIdx.x;
  if (bid < DD) {
    int d = bid;
    double s = 0.0;
    for (int b = tid; b < BB; b += 256) s += 1.0 - (double)xT[(size_t)d * BB + b];
    red[tid] = s;
    __syncthreads();
    for (int st = 128; st > 0; st >>= 1) {
      if (tid < st) red[tid] += red[tid + st];
      __syncthreads();
    }
    if (tid == 0) Sx[d] = red[0];
  } else {
    int o = bid - DD;
    double s = 0.0, wt = 0.0;
    for (int d = tid; d < DD; d += 256) {
      double wv = (double)w[(size_t)d * OO + o];
      s += 1.0 - wv;
      wt += wv;
    }
    red[tid] = s;
    __syncthreads();
    for (int st = 128; st > 0; st >>= 1) {
      if (tid < st) red[tid] += red[tid + st];
      __syncthreads();
    }
    if (tid == 0) Sw[o] = red[0];
    __syncthreads();
    red[tid] = wt;
    __syncthreads();
    for (int st = 128; st > 0; st >>= 1) {
      if (tid < st) red[tid] += red[tid + st];
      __syncthreads();
    }
    if (tid == 0) Wtot[o] = red[0];
  }
}

// ---------------------------------------------------------------------------
// k2_part: partial sums of sum_b max(x[b,d], t[b,o]) over a B_TILE slab.
// grid (DD/D_TILE, B_SPLIT) = 1024 blocks; block = 256 threads (one o each).
// x tile staged in LDS (broadcast reads); t reads coalesced across lanes.
// f64 pair-tree accumulation: chain depth B_TILE/4 per acc, 4 indep accs.
// ---------------------------------------------------------------------------
__global__ __launch_bounds__(256) void k2_part(const float* __restrict__ xT,
                                               const float* __restrict__ t,
                                               double* __restrict__ part) {
  int o = threadIdx.x;
  int d0 = blockIdx.x * D_TILE;
  int b0 = blockIdx.y * B_TILE;
  __shared__ float xl[D_TILE][B_TILE];
  for (int i = threadIdx.x; i < D_TILE * B_TILE; i += 256) {
    int dd = i / B_TILE, bb = i % B_TILE;
    xl[dd][bb] = xT[(size_t)(d0 + dd) * BB + b0 + bb];
  }
  __syncthreads();

  double acc[D_TILE] = {0.0, 0.0, 0.0, 0.0};
  for (int bb = 0; bb < B_TILE; bb += 4) {
    float tv0 = t[(size_t)(b0 + bb + 0) * OO + o];
    float tv1 = t[(size_t)(b0 + bb + 1) * OO + o];
    float tv2 = t[(size_t)(b0 + bb + 2) * OO + o];
    float tv3 = t[(size_t)(b0 + bb + 3) * OO + o];
#pragma unroll
    for (int dd = 0; dd < D_TILE; ++dd) {
      double s01 = (double)fmaxf(xl[dd][bb + 0], tv0) +
                   (double)fmaxf(xl[dd][bb + 1], tv1);
      double s23 = (double)fmaxf(xl[dd][bb + 2], tv2) +
                   (double)fmaxf(xl[dd][bb + 3], tv3);
      acc[dd] += (s01 + s23);
    }
  }
#pragma unroll
  for (int dd = 0; dd < D_TILE; ++dd)
    part[((size_t)(d0 + dd) * B_SPLIT + blockIdx.y) * OO + o] = acc[dd];
}

// ---------------------------------------------------------------------------
// k2b: combine B_SPLIT partials -> relx[d,o] = 1 - (B - a)/Sx[d]
// ---------------------------------------------------------------------------
__global__ __launch_bounds__(256) void k2b_combine(const double* __restrict__ part,
                                                   const double* __restrict__ Sx,
                                                   double* __restrict__ relx) {
  int o = threadIdx.x;
  int d = blockIdx.x;
  const double* p = part + (size_t)d * B_SPLIT * OO + o;
  double a = 0.0;
#pragma unroll
  for (int s = 0; s < B_SPLIT; ++s) a += p[(size_t)s * OO];
  relx[(size_t)d * OO + o] = 1.0 - ((double)BB - a) / Sx[d];
}

// ---------------------------------------------------------------------------
// k3: per-o sorting. grid 512: bid<OO -> w column (sort+scan+prefix-min);
// bid>=OO -> relx column (sort only). Bitonic with lexicographic (key,idx).
// ---------------------------------------------------------------------------
__device__ void bitonic512(double* key, int* idx, int tid) {
  for (int k = 2; k <= 512; k <<= 1) {
    for (int j = k >> 1; j > 0; j >>= 1) {
      __syncthreads();
      for (int i = tid; i < 512; i += 256) {
        int p = i ^ j;
        if (p > i) {
          double ka = key[i], kb = key[p];
          int ia = idx[i], ib = idx[p];
          bool up = ((i & k) == 0);
          bool agtb = (ka > kb) || (ka == kb && ia > ib);
          if (up == agtb) {
            key[i] = kb; key[p] = ka;
            idx[i] = ib; idx[p] = ia;
          }
        }
      }
    }
  }
  __syncthreads();
}

__global__ __launch_bounds__(256) void k3_sort(const float* __restrict__ w,
                                               const double* __restrict__ relx,
                                               double* __restrict__ wpre,
                                               double* __restrict__ rxv,
                                               float* __restrict__ wsrt,
                                               int* __restrict__ pm,
                                               int* __restrict__ rxi) {
  int bid = blockIdx.x;
  int o = bid & (OO - 1);
  int tid = threadIdx.x;
  __shared__ double key[512];
  __shared__ int idx[512];
  __shared__ double scn[512];
  __shared__ int mn[512];

  if (bid < OO) {
    // ---- w column: sort + inclusive scan (sum) + prefix-min of idx ----
    for (int i = tid; i < 512; i += 256) {
      key[i] = (double)w[(size_t)i * OO + o];
      idx[i] = i;
    }
    bitonic512(key, idx, tid);
    for (int i = tid; i < 512; i += 256) {
      scn[i] = key[i];
      mn[i] = idx[i];
    }
    for (int off = 1; off < 512; off <<= 1) {
      double v0, v1;
      int m0, m1;
      __syncthreads();
      {
        int i0 = tid, i1 = tid + 256;
        v0 = (i0 >= off) ? scn[i0 - off] : 0.0;
        v1 = (i1 >= off) ? scn[i1 - off] : 0.0;
        m0 = (i0 >= off) ? mn[i0 - off] : 0x7fffffff;
        m1 = (i1 >= off) ? mn[i1 - off] : 0x7fffffff;
      }
      __syncthreads();
      {
        int i0 = tid, i1 = tid + 256;
        scn[i0] += v0; scn[i1] += v1;
        mn[i0] = mn[i0] < m0 ? mn[i0] : m0;
        mn[i1] = mn[i1] < m1 ? mn[i1] : m1;
      }
    }
    __syncthreads();
    for (int i = tid; i < 512; i += 256) {
      wsrt[(size_t)o * 512 + i] = (float)key[i];
      wpre[(size_t)o * 512 + i] = scn[i];
      pm[(size_t)o * 512 + i] = mn[i];
    }
  } else {
    // ---- rel_x column: sort only ----
    for (int i = tid; i < 512; i += 256) {
      key[i] = relx[(size_t)i * OO + o];
      idx[i] = i;
    }
    bitonic512(key, idx, tid);
    for (int i = tid; i < 512; i += 256) {
      rxv[(size_t)o * 512 + i] = key[i];
      rxi[(size_t)o * 512 + i] = idx[i];
    }
  }
}

// ---------------------------------------------------------------------------
// k4: per (b,o): rel_w via binary search + prefix sums; ind_w via binary
// search + prefix-min; ind_x via early-exit scan in ascending rel_x order.
// ---------------------------------------------------------------------------
__global__ __launch_bounds__(256) void k4_final(
    const float* __restrict__ xT, const float* __restrict__ w,
    const float* __restrict__ t, const double* __restrict__ Sw,
    const double* __restrict__ Wtot, const double* __restrict__ wpre,
    const double* __restrict__ rxv, const float* __restrict__ wsrt,
    const int* __restrict__ pm, const int* __restrict__ rxi,
    float* __restrict__ out) {
  int o = blockIdx.x;
  int tid = threadIdx.x;
  int b = blockIdx.y * 256 + tid;

  __shared__ float wsr_l[512];
  __shared__ double wpre_l[513];
  __shared__ double rxv_l[512];
  __shared__ int pm_l[512];
  __shared__ int rxi_l[512];

  for (int i = tid; i < 512; i += 256) {
    wsr_l[i] = wsrt[(size_t)o * 512 + i];
    wpre_l[i + 1] = wpre[(size_t)o * 512 + i];
    rxv_l[i] = rxv[(size_t)o * 512 + i];
    pm_l[i] = pm[(size_t)o * 512 + i];
    rxi_l[i] = rxi[(size_t)o * 512 + i];
  }
  if (tid == 0) wpre_l[0] = 0.0;
  __syncthreads();

  float c = t[(size_t)b * OO + o];

  // k = #{d : w[d,o] <= c}
  int lo = 0, hi = 512;
  while (lo < hi) {
    int mid = (lo + hi) >> 1;
    if (wsr_l[mid] <= c) lo = mid + 1; else hi = mid;
  }
  int k = lo;
  double smax = (Wtot[o] - wpre_l[k]) + (double)c * (double)k;
  double relw = 1.0 - ((double)DD - smax) / Sw[o];

  // #{d : (double)w[d,o] <= relw}
  lo = 0; hi = 512;
  while (lo < hi) {
    int mid = (lo + hi) >> 1;
    if ((double)wsr_l[mid] <= relw) lo = mid + 1; else hi = mid;
  }
  int iw = pm_l[(lo > 0) ? (lo - 1) : 0];

  // ind_x: argmin_d max(x[b,d], rel_x[d,o]) via early-exit over sorted rel_x
  double best = 1e300;
  int bix = 0x7fffffff;
  float xpf[8];
  int dpf[8];
  double rpf[8];
#pragma unroll
  for (int j = 0; j < 8; ++j) {
    dpf[j] = rxi_l[j];
    rpf[j] = rxv_l[j];
    xpf[j] = xT[(size_t)dpf[j] * BB + b];
  }
  bool done = false;
#pragma unroll
  for (int j = 0; j < 8; ++j) {
    if (!done) {
      if (rpf[j] > best) {
        done = true;
      } else {
        double v = fmax((double)xpf[j], rpf[j]);
        if (v < best || (v == best && dpf[j] < bix)) { best = v; bix = dpf[j]; }
      }
    }
  }
  if (!done) {
    for (int j = 8; j < 512; ++j) {
      double rj = rxv_l[j];
      if (rj > best) break;
      int dj = rxi_l[j];
      double v = fmax((double)xT[(size_t)dj * BB + b], rj);
      if (v < best || (v == best && dj < bix)) { best = v; bix = dj; }
    }
  }

  float ox = fmaxf(xT[(size_t)bix * BB + b], w[(size_t)bix * OO + o]);
  float ow = fmaxf(xT[(size_t)iw * BB + b], w[(size_t)iw * OO + o]);
  out[(size_t)b * OO + o] = ox;
  out[(size_t)BB * OO + (size_t)b * OO + o] = ow;
}

// ---------------------------------------------------------------------------
extern "C" void kernel_launch(void* const* d_in, const int* in_sizes, int n_in,
                              void* d_out, int out_size, void* d_ws,
                              size_t ws_size, hipStream_t stream) {
  const float* x = (const float*)d_in[0];  // (B,D)
  const float* w = (const float*)d_in[1];  // (D,O)
  const float* t = (const float*)d_in[2];  // (B,O)
  float* out = (float*)d_out;
  char* ws = (char*)d_ws;

  // Persistent region
  size_t off = 0;
  float* xT    = (float*)(ws + off);  off += (size_t)BB * DD * 4;        // 2 MB
  double* relx = (double*)(ws + off); off += (size_t)DD * OO * 8;        // 1 MB
  double* Sx   = (double*)(ws + off); off += (size_t)DD * 8;
  double* Sw   = (double*)(ws + off); off += (size_t)OO * 8;
  double* Wtot = (double*)(ws + off); off += (size_t)OO * 8;

  // Region B: part (8 MB, dead after k2b) overlaid with k3 outputs (3.5 MB,
  // written only in k3 which runs after k2b). Safe union.
  char* regB = ws + off;
  double* part = (double*)regB;  // DD * B_SPLIT * OO * 8 = 8 MB
  size_t boff = 0;
  double* wpre = (double*)(regB + boff); boff += (size_t)OO * DD * 8;    // 1 MB
  double* rxv  = (double*)(regB + boff); boff += (size_t)OO * DD * 8;    // 1 MB
  float* wsrt  = (float*)(regB + boff);  boff += (size_t)OO * DD * 4;    // .5 MB
  int* pm      = (int*)(regB + boff);    boff += (size_t)OO * DD * 4;    // .5 MB
  int* rxi     = (int*)(regB + boff);    boff += (size_t)OO * DD * 4;    // .5 MB

  k0_transpose<<<dim3(BB / 32, DD / 32), dim3(32, 8), 0, stream>>>(x, xT);
  k1_sums<<<DD + OO, 256, 0, stream>>>(xT, w, Sx, Sw, Wtot);
  k2_part<<<dim3(DD / D_TILE, B_SPLIT), 256, 0, stream>>>(xT, t, part);
  k2b_combine<<<DD, 256, 0, stream>>>(part, Sx, relx);
  k3_sort<<<2 * OO, 256, 0, stream>>>(w, relx, wpre, rxv, wsrt, pm, rxi);
  k4_final<<<dim3(OO, BB / 256), 256, 0, stream>>>(xT, w, t, Sw, Wtot, wpre,
                                                   rxv, wsrt, pm, rxi, out);
}

// Round 3
// 67.947 us; speedup vs baseline: 2.1057x; 1.2078x over previous
//
#include <hip/hip_runtime.h>

#define BB 1024
#define DD 512
#define OO 256

// ===========================================================================
// kA: all-independent roles in one launch:
//   P  (512 blocks): partial sums  part[s][d][o] = sum_{b in slab s} max(x[b,d], t[b,o])
//   T  (512 blocks): transpose x -> xT[d][b]
//   Tt (256 blocks): transpose t -> tT[o][b]
//   W  (128 blocks): transpose w -> wT[o][d]
//   S  ( 16 blocks): Sx partials Sxp[s][d] = sum_{b in slab s} (1 - x[b,d])
// ===========================================================================
__global__ __launch_bounds__(256) void kA(const float* __restrict__ x,
                                          const float* __restrict__ w,
                                          const float* __restrict__ t,
                                          float* __restrict__ xT,
                                          float* __restrict__ tT,
                                          float* __restrict__ wT,
                                          double* __restrict__ Sxp,
                                          double* __restrict__ part) {
  __shared__ float smem[32 * 33];  // 4224 floats? no: 1056 floats = 4224 B
  int bid = blockIdx.x, tid = threadIdx.x;
  if (bid < 512) {
    // ---- role P ----
    float (*xl)[132] = (float(*)[132])smem;  // 8*132 = 1056 floats
    int dg = bid >> 3, sy = bid & 7;
    int d0 = dg * 8, b0 = sy * 128, o = tid;
    for (int i = tid; i < 1024; i += 256) {
      int bb = i >> 3, dd = i & 7;
      xl[dd][bb] = x[(b0 + bb) * DD + d0 + dd];
    }
    __syncthreads();
    double acc[8] = {0, 0, 0, 0, 0, 0, 0, 0};
    for (int bb = 0; bb < 128; bb += 2) {
      float tv0 = t[(b0 + bb) * OO + o];
      float tv1 = t[(b0 + bb + 1) * OO + o];
#pragma unroll
      for (int dd = 0; dd < 8; ++dd)
        acc[dd] += (double)fmaxf(xl[dd][bb], tv0) + (double)fmaxf(xl[dd][bb + 1], tv1);
    }
#pragma unroll
    for (int dd = 0; dd < 8; ++dd)
      part[(sy * DD + d0 + dd) * OO + o] = acc[dd];
  } else if (bid < 1024) {
    // ---- role T: x (1024x512) -> xT (512x1024) ----
    float (*tile)[33] = (float(*)[33])smem;
    int r = bid - 512;
    int b0 = (r & 31) * 32, d0 = (r >> 5) * 32;
    int tx = tid & 31, ty = tid >> 5;
    for (int i = 0; i < 32; i += 8)
      tile[ty + i][tx] = x[(b0 + ty + i) * DD + d0 + tx];
    __syncthreads();
    for (int i = 0; i < 32; i += 8)
      xT[(d0 + ty + i) * BB + b0 + tx] = tile[tx][ty + i];
  } else if (bid < 1280) {
    // ---- role Tt: t (1024x256) -> tT (256x1024) ----
    float (*tile)[33] = (float(*)[33])smem;
    int r = bid - 1024;
    int b0 = (r & 31) * 32, o0 = (r >> 5) * 32;
    int tx = tid & 31, ty = tid >> 5;
    for (int i = 0; i < 32; i += 8)
      tile[ty + i][tx] = t[(b0 + ty + i) * OO + o0 + tx];
    __syncthreads();
    for (int i = 0; i < 32; i += 8)
      tT[(o0 + ty + i) * BB + b0 + tx] = tile[tx][ty + i];
  } else if (bid < 1408) {
    // ---- role W: w (512x256) -> wT (256x512) ----
    float (*tile)[33] = (float(*)[33])smem;
    int r = bid - 1280;
    int d0 = (r & 15) * 32, o0 = (r >> 4) * 32;
    int tx = tid & 31, ty = tid >> 5;
    for (int i = 0; i < 32; i += 8)
      tile[ty + i][tx] = w[(d0 + ty + i) * OO + o0 + tx];
    __syncthreads();
    for (int i = 0; i < 32; i += 8)
      wT[(o0 + ty + i) * DD + d0 + tx] = tile[tx][ty + i];
  } else {
    // ---- role S ----
    int r = bid - 1408;  // 0..15
    int sy = r & 7, dh = r >> 3;
    int d = dh * 256 + tid, b0 = sy * 128;
    double s = 0.0;
    for (int b = b0; b < b0 + 128; ++b) s += 1.0 - (double)x[b * DD + d];
    Sxp[sy * DD + d] = s;
  }
}

// ===========================================================================
// kB: per-o tables.
//  bid < 256 (WB, o=bid): bucket w column by value (512 buckets over [0,1)),
//    idx-sort each bucket (determinism of f64 sums), exclusive prefix sum P
//    and prefix-min Mx over the bucketed array, bucket offsets off, gmin.
//  bid >= 256 (RX, o=bid-256): combine Sx partials + part -> relx column,
//    bucket by value over [rmin,rmax], scatter (rv, ri, eb=safe bucket lower
//    bound) — no sort needed (queries are set-based).
// ===========================================================================
__global__ __launch_bounds__(256) void kB(const float* __restrict__ wT,
                                          const double* __restrict__ Sxp,
                                          const double* __restrict__ part,
                                          float* __restrict__ sv_g,
                                          int* __restrict__ si_g,
                                          int* __restrict__ off_g,
                                          double* __restrict__ P_g,
                                          int* __restrict__ Mx_g,
                                          double* __restrict__ rv_g,
                                          int* __restrict__ ri_g,
                                          double* __restrict__ eb_g,
                                          double* __restrict__ hdrW,
                                          int* __restrict__ gmin_g) {
  int bid = blockIdx.x, tid = threadIdx.x;
  int lane = tid & 63, wid = tid >> 6;
  if (bid < OO) {
    int o = bid;
    __shared__ float sv[512];
    __shared__ int si[512];
    __shared__ int cnt[512];
    __shared__ int off[513];
    __shared__ double P[513];
    __shared__ int Mx[513];
    __shared__ double wsc[4];
    __shared__ int wmn[4];
    __shared__ unsigned long long wk[4];
    int i0 = 2 * tid, i1 = 2 * tid + 1;
    float w0 = wT[o * DD + i0], w1 = wT[o * DD + i1];
    cnt[i0] = 0; cnt[i1] = 0;
    __syncthreads();
    int q0 = min(511, max(0, (int)(w0 * 512.0f)));
    int q1 = min(511, max(0, (int)(w1 * 512.0f)));
    int sl0 = atomicAdd(&cnt[q0], 1);
    int sl1 = atomicAdd(&cnt[q1], 1);
    __syncthreads();
    // off = exclusive scan of cnt (shuffle-based, 2 barriers)
    {
      int e0 = cnt[i0], e1 = cnt[i1];
      int s = e0 + e1, v = s;
      for (int d = 1; d < 64; d <<= 1) {
        int u = __shfl_up(v, d);
        if (lane >= d) v += u;
      }
      if (lane == 63) wmn[wid] = v;
      __syncthreads();
      int wp = 0;
      for (int u = 0; u < wid; ++u) wp += wmn[u];
      int ex = wp + (v - s);
      off[i0] = ex; off[i1] = ex + e0;
      if (tid == 255) off[512] = ex + s;
      __syncthreads();
    }
    // scatter
    sv[off[q0] + sl0] = w0; si[off[q0] + sl0] = i0;
    sv[off[q1] + sl1] = w1; si[off[q1] + sl1] = i1;
    __syncthreads();
    // per-bucket insertion sort by original index (determinism)
    for (int q = tid; q < 512; q += 256) {
      int s = off[q], e = off[q + 1];
      for (int i = s + 1; i < e; ++i) {
        int ki = si[i]; float kv = sv[i]; int j = i - 1;
        while (j >= s && si[j] > ki) { si[j + 1] = si[j]; sv[j + 1] = sv[j]; --j; }
        si[j + 1] = ki; sv[j + 1] = kv;
      }
    }
    __syncthreads();
    // P: exclusive f64 prefix-sum of sv; Mx: exclusive prefix-min of si
    {
      double e0 = (double)sv[i0], e1 = (double)sv[i1];
      int m0 = si[i0], m1 = si[i1];
      double s = e0 + e1; int mm = min(m0, m1);
      double vs = s; int vm = mm;
      for (int d = 1; d < 64; d <<= 1) {
        double us = __shfl_up(vs, d);
        int um = __shfl_up(vm, d);
        if (lane >= d) { vs += us; vm = min(vm, um); }
      }
      double exs = __shfl_up(vs, 1);
      int exm = __shfl_up(vm, 1);
      if (lane == 0) { exs = 0.0; exm = 0x7fffffff; }
      if (lane == 63) { wsc[wid] = vs; wmn[wid] = vm; }
      __syncthreads();
      double wp = 0.0; int wm = 0x7fffffff;
      for (int u = 0; u < wid; ++u) { wp += wsc[u]; wm = min(wm, wmn[u]); }
      double EX = wp + exs; int EXM = min(wm, exm);
      P[i0] = EX; P[i1] = EX + e0;
      Mx[i0] = EXM; Mx[i1] = min(EXM, m0);
      if (tid == 255) { P[512] = EX + s; Mx[512] = min(EXM, mm); }
      __syncthreads();
    }
    // gmin: lexicographic (w, idx) min
    {
      unsigned long long k0 = ((unsigned long long)__float_as_uint(sv[i0]) << 32) | (unsigned)si[i0];
      unsigned long long k1 = ((unsigned long long)__float_as_uint(sv[i1]) << 32) | (unsigned)si[i1];
      unsigned long long kk = k0 < k1 ? k0 : k1;
      for (int d = 32; d > 0; d >>= 1) {
        unsigned long long u = __shfl_down(kk, d);
        kk = u < kk ? u : kk;
      }
      if (lane == 0) wk[wid] = kk;
      __syncthreads();
      if (tid == 0) {
        unsigned long long g = wk[0];
        for (int u = 1; u < 4; ++u) g = wk[u] < g ? wk[u] : g;
        gmin_g[o] = (int)(g & 0xffffffffull);
      }
    }
    // write out
    for (int i = tid; i < 512; i += 256) {
      sv_g[o * 512 + i] = sv[i];
      si_g[o * 512 + i] = si[i];
    }
    for (int i = tid; i < 513; i += 256) {
      off_g[o * 513 + i] = off[i];
      P_g[o * 513 + i] = P[i];
      Mx_g[o * 513 + i] = Mx[i];
    }
    if (tid == 0) { hdrW[o * 2 + 0] = 512.0 - P[512]; hdrW[o * 2 + 1] = P[512]; }
  } else {
    int o = bid - OO;
    __shared__ double rl[512];
    __shared__ int cnt2[512];
    __shared__ int roff[513];
    __shared__ double rv[512];
    __shared__ int ri[512];
    __shared__ double eb[512];
    __shared__ double wred[8];
    __shared__ int wint[4];
    int i0 = 2 * tid, i1 = 2 * tid + 1;
    // Sx combine + part combine -> relx column
    {
      double sx0 = 0.0, sx1 = 0.0, a0 = 0.0, a1 = 0.0;
#pragma unroll
      for (int s = 0; s < 8; ++s) {
        sx0 += Sxp[s * DD + i0];
        sx1 += Sxp[s * DD + i1];
        a0 += part[(s * DD + i0) * OO + o];
        a1 += part[(s * DD + i1) * OO + o];
      }
      rl[i0] = 1.0 - (1024.0 - a0) / sx0;
      rl[i1] = 1.0 - (1024.0 - a1) / sx1;
    }
    // rmin/rmax reduce
    double mn = fmin(rl[i0], rl[i1]), mx = fmax(rl[i0], rl[i1]);
    for (int d = 32; d > 0; d >>= 1) {
      mn = fmin(mn, __shfl_down(mn, d));
      mx = fmax(mx, __shfl_down(mx, d));
    }
    if (lane == 0) { wred[wid] = mn; wred[4 + wid] = mx; }
    cnt2[i0] = 0; cnt2[i1] = 0;
    __syncthreads();
    double rmin = fmin(fmin(wred[0], wred[1]), fmin(wred[2], wred[3]));
    double rmax = fmax(fmax(wred[4], wred[5]), fmax(wred[6], wred[7]));
    double range = rmax - rmin;
    double scale = (range > 0.0) ? (512.0 / range) : 0.0;
    double bw = range * (1.0 / 512.0);
    double base = rmin - range * 1e-9;
    int q0 = min(511, max(0, (int)((rl[i0] - rmin) * scale)));
    int q1 = min(511, max(0, (int)((rl[i1] - rmin) * scale)));
    int sl0 = atomicAdd(&cnt2[q0], 1);
    int sl1 = atomicAdd(&cnt2[q1], 1);
    __syncthreads();
    // roff = exclusive scan of cnt2
    {
      int e0 = cnt2[i0], e1 = cnt2[i1];
      int s = e0 + e1, v = s;
      for (int d = 1; d < 64; d <<= 1) {
        int u = __shfl_up(v, d);
        if (lane >= d) v += u;
      }
      if (lane == 63) wint[wid] = v;
      __syncthreads();
      int wp = 0;
      for (int u = 0; u < wid; ++u) wp += wint[u];
      int ex = wp + (v - s);
      roff[i0] = ex; roff[i1] = ex + e0;
      if (tid == 255) roff[512] = ex + s;
      __syncthreads();
    }
    // scatter (order within bucket nondeterministic — queries are set-based)
    {
      int p0 = roff[q0] + sl0, p1 = roff[q1] + sl1;
      rv[p0] = rl[i0]; ri[p0] = i0; eb[p0] = base + (double)q0 * bw;
      rv[p1] = rl[i1]; ri[p1] = i1; eb[p1] = base + (double)q1 * bw;
    }
    __syncthreads();
    for (int i = tid; i < 512; i += 256) {
      rv_g[o * 512 + i] = rv[i];
      ri_g[o * 512 + i] = ri[i];
      eb_g[o * 512 + i] = eb[i];
    }
  }
}

// ===========================================================================
// kC: per (b,o) queries. block = one o x 256 b's; grid (256, 4).
//  Q1: k & prefix-sum of {w <= c} via bucket lookup -> rel_w
//  Q2: min-idx of {w <= rel_w} via bucket lookup (else gmin)
//  RX: argmin_d max(x,relx) via bucketed ascending scan, eb[i]>best break
// ===========================================================================
__global__ __launch_bounds__(256) void kC(
    const float* __restrict__ xT, const float* __restrict__ wT,
    const float* __restrict__ tT, const float* __restrict__ sv_g,
    const int* __restrict__ si_g, const int* __restrict__ off_g,
    const double* __restrict__ P_g, const int* __restrict__ Mx_g,
    const double* __restrict__ rv_g, const int* __restrict__ ri_g,
    const double* __restrict__ eb_g, const double* __restrict__ hdrW,
    const int* __restrict__ gmin_g, float* __restrict__ out) {
  int o = blockIdx.x, tid = threadIdx.x;
  int b = blockIdx.y * 256 + tid;
  __shared__ float sv[512];
  __shared__ int si[512];
  __shared__ int off[513];
  __shared__ double P[513];
  __shared__ int Mx[513];
  __shared__ double rv[512];
  __shared__ int ri[512];
  __shared__ double eb[512];
  for (int i = tid; i < 512; i += 256) {
    sv[i] = sv_g[o * 512 + i];
    si[i] = si_g[o * 512 + i];
    rv[i] = rv_g[o * 512 + i];
    ri[i] = ri_g[o * 512 + i];
    eb[i] = eb_g[o * 512 + i];
  }
  for (int i = tid; i < 513; i += 256) {
    off[i] = off_g[o * 513 + i];
    P[i] = P_g[o * 513 + i];
    Mx[i] = Mx_g[o * 513 + i];
  }
  __syncthreads();
  double Sw = hdrW[o * 2 + 0], Wtot = hdrW[o * 2 + 1];
  float c = tT[o * BB + b];
  // Q1
  int j = min(511, max(0, (int)(c * 512.0f)));
  int s0 = off[j], e0 = off[j + 1];
  double pre = P[s0];
  int k = s0;
  for (int i = s0; i < e0; ++i) {
    float wv = sv[i];
    if (wv <= c) { pre += (double)wv; ++k; }
  }
  double smax = (Wtot - pre) + (double)c * (double)k;
  double relw = 1.0 - (512.0 - smax) / Sw;
  // Q2
  int j2t = (int)(relw * 512.0);
  int j2 = min(511, max(0, j2t));
  int s2 = off[j2], e2 = off[j2 + 1];
  int iw = Mx[s2];
  for (int i = s2; i < e2; ++i)
    if ((double)sv[i] <= relw) iw = min(iw, si[i]);
  if (iw == 0x7fffffff) iw = gmin_g[o];
  // RX argmin with prefetched first 8 gathers
  float x0 = xT[ri[0] * BB + b], x1 = xT[ri[1] * BB + b];
  float x2 = xT[ri[2] * BB + b], x3 = xT[ri[3] * BB + b];
  float x4 = xT[ri[4] * BB + b], x5 = xT[ri[5] * BB + b];
  float x6 = xT[ri[6] * BB + b], x7 = xT[ri[7] * BB + b];
  double best = 1e300;
  int bix = 0x7fffffff;
  for (int i = 0; i < 512; ++i) {
    if (eb[i] > best) break;
    int dj = ri[i];
    float xv;
    if (i < 8) {
      xv = (i == 0) ? x0 : (i == 1) ? x1 : (i == 2) ? x2 : (i == 3) ? x3
         : (i == 4) ? x4 : (i == 5) ? x5 : (i == 6) ? x6 : x7;
    } else {
      xv = xT[dj * BB + b];
    }
    double v = fmax((double)xv, rv[i]);
    if (v < best || (v == best && dj < bix)) { best = v; bix = dj; }
  }
  float ox = fmaxf(xT[bix * BB + b], wT[o * DD + bix]);
  float ow = fmaxf(xT[iw * BB + b], wT[o * DD + iw]);
  out[b * OO + o] = ox;
  out[BB * OO + b * OO + o] = ow;
}

// ===========================================================================
extern "C" void kernel_launch(void* const* d_in, const int* in_sizes, int n_in,
                              void* d_out, int out_size, void* d_ws,
                              size_t ws_size, hipStream_t stream) {
  const float* x = (const float*)d_in[0];  // (B,D)
  const float* w = (const float*)d_in[1];  // (D,O)
  const float* t = (const float*)d_in[2];  // (B,O)
  float* out = (float*)d_out;
  char* ws = (char*)d_ws;

  size_t off = 0;
  float* xT    = (float*)(ws + off);  off += (size_t)DD * BB * 4;       // 2 MB
  float* tT    = (float*)(ws + off);  off += (size_t)OO * BB * 4;       // 1 MB
  float* wT    = (float*)(ws + off);  off += (size_t)OO * DD * 4;       // .5 MB
  double* Sxp  = (double*)(ws + off); off += (size_t)8 * DD * 8;        // 32 KB
  double* part = (double*)(ws + off); off += (size_t)8 * DD * OO * 8;   // 8 MB
  float* sv_g  = (float*)(ws + off);  off += (size_t)OO * 512 * 4;
  int* si_g    = (int*)(ws + off);    off += (size_t)OO * 512 * 4;
  int* off_g   = (int*)(ws + off);    off += (size_t)OO * 513 * 4;
  double* P_g  = (double*)(ws + off); off += (size_t)OO * 513 * 8;
  int* Mx_g    = (int*)(ws + off);    off += (size_t)OO * 513 * 4;
  double* rv_g = (double*)(ws + off); off += (size_t)OO * 512 * 8;
  int* ri_g    = (int*)(ws + off);    off += (size_t)OO * 512 * 4;
  double* eb_g = (double*)(ws + off); off += (size_t)OO * 512 * 8;
  double* hdrW = (double*)(ws + off); off += (size_t)OO * 2 * 8;
  int* gmin_g  = (int*)(ws + off);    off += (size_t)OO * 4;

  kA<<<1424, 256, 0, stream>>>(x, w, t, xT, tT, wT, Sxp, part);
  kB<<<2 * OO, 256, 0, stream>>>(wT, Sxp, part, sv_g, si_g, off_g, P_g, Mx_g,
                                 rv_g, ri_g, eb_g, hdrW, gmin_g);
  kC<<<dim3(OO, BB / 256), 256, 0, stream>>>(xT, wT, tT, sv_g, si_g, off_g,
                                             P_g, Mx_g, rv_g, ri_g, eb_g,
                                             hdrW, gmin_g, out);
}

// Round 4
// 63.984 us; speedup vs baseline: 2.2361x; 1.0619x over previous
//
#include <hip/hip_runtime.h>

#define BB 1024
#define DD 512
#define OO 256

// ===========================================================================
// kA: all-independent roles in one launch:
//   P  (512 blocks): part[s][d][o] = sum_{b in slab s} max(x[b,d], t[b,o])
//   T  (512 blocks): transpose x -> xT[d][b]
//   Tt (256 blocks): transpose t -> tT[o][b]
//   W  (128 blocks): transpose w -> wT[o][d]
//   S  ( 16 blocks): Sxp[s][d] = sum_{b in slab s} (1 - x[b,d])
// ===========================================================================
__global__ __launch_bounds__(256) void kA(const float* __restrict__ x,
                                          const float* __restrict__ w,
                                          const float* __restrict__ t,
                                          float* __restrict__ xT,
                                          float* __restrict__ tT,
                                          float* __restrict__ wT,
                                          double* __restrict__ Sxp,
                                          double* __restrict__ part) {
  __shared__ float smem[8 * 136];  // 4352 B; transpose roles use 32*33 <= this
  int bid = blockIdx.x, tid = threadIdx.x;
  if (bid < 512) {
    // ---- role P ----
    float (*xl)[136] = (float(*)[136])smem;  // row stride 544B (16B aligned)
    int dg = bid >> 3, sy = bid & 7;
    int d0 = dg * 8, b0 = sy * 128, o = tid;
    {
      int bb = tid >> 1, half = tid & 1;
      float4 g = *(const float4*)&x[(b0 + bb) * DD + d0 + half * 4];
      xl[half * 4 + 0][bb] = g.x;
      xl[half * 4 + 1][bb] = g.y;
      xl[half * 4 + 2][bb] = g.z;
      xl[half * 4 + 3][bb] = g.w;
    }
    __syncthreads();
    double acc[8] = {0, 0, 0, 0, 0, 0, 0, 0};
    for (int bb = 0; bb < 128; bb += 4) {
      float tv0 = t[(b0 + bb + 0) * OO + o];
      float tv1 = t[(b0 + bb + 1) * OO + o];
      float tv2 = t[(b0 + bb + 2) * OO + o];
      float tv3 = t[(b0 + bb + 3) * OO + o];
#pragma unroll
      for (int dd = 0; dd < 8; ++dd) {
        float4 xv = *(const float4*)&xl[dd][bb];
        double s01 = (double)fmaxf(xv.x, tv0) + (double)fmaxf(xv.y, tv1);
        double s23 = (double)fmaxf(xv.z, tv2) + (double)fmaxf(xv.w, tv3);
        acc[dd] += s01 + s23;
      }
    }
#pragma unroll
    for (int dd = 0; dd < 8; ++dd)
      part[(sy * DD + d0 + dd) * OO + o] = acc[dd];
  } else if (bid < 1024) {
    // ---- role T: x (1024x512) -> xT (512x1024) ----
    float (*tile)[33] = (float(*)[33])smem;
    int r = bid - 512;
    int b0 = (r & 31) * 32, d0 = (r >> 5) * 32;
    int tx = tid & 31, ty = tid >> 5;
    for (int i = 0; i < 32; i += 8)
      tile[ty + i][tx] = x[(b0 + ty + i) * DD + d0 + tx];
    __syncthreads();
    for (int i = 0; i < 32; i += 8)
      xT[(d0 + ty + i) * BB + b0 + tx] = tile[tx][ty + i];
  } else if (bid < 1280) {
    // ---- role Tt: t (1024x256) -> tT (256x1024) ----
    float (*tile)[33] = (float(*)[33])smem;
    int r = bid - 1024;
    int b0 = (r & 31) * 32, o0 = (r >> 5) * 32;
    int tx = tid & 31, ty = tid >> 5;
    for (int i = 0; i < 32; i += 8)
      tile[ty + i][tx] = t[(b0 + ty + i) * OO + o0 + tx];
    __syncthreads();
    for (int i = 0; i < 32; i += 8)
      tT[(o0 + ty + i) * BB + b0 + tx] = tile[tx][ty + i];
  } else if (bid < 1408) {
    // ---- role W: w (512x256) -> wT (256x512) ----
    float (*tile)[33] = (float(*)[33])smem;
    int r = bid - 1280;
    int d0 = (r & 15) * 32, o0 = (r >> 4) * 32;
    int tx = tid & 31, ty = tid >> 5;
    for (int i = 0; i < 32; i += 8)
      tile[ty + i][tx] = w[(d0 + ty + i) * OO + o0 + tx];
    __syncthreads();
    for (int i = 0; i < 32; i += 8)
      wT[(o0 + ty + i) * DD + d0 + tx] = tile[tx][ty + i];
  } else {
    // ---- role S ----
    int r = bid - 1408;  // 0..15
    int sy = r & 7, dh = r >> 3;
    int d = dh * 256 + tid, b0 = sy * 128;
    double s = 0.0;
    for (int b = b0; b < b0 + 128; ++b) s += 1.0 - (double)x[b * DD + d];
    Sxp[sy * DD + d] = s;
  }
}

// ===========================================================================
// kB: per-o tables.
//  bid < 256 (WB): bucket w column (512 buckets over [0,1), trunc quantizer),
//    idx-sort buckets (f64 determinism), exclusive prefix sum P / prefix-min
//    Mx, bucket offsets, global lexicographic min.
//  bid >= 256 (RX): combine partials -> relx column, bucket by value over
//    [rmin,rmax]; eb = round-DOWN f32 bucket lower bound (safe break bound).
// ===========================================================================
__global__ __launch_bounds__(256) void kB(const float* __restrict__ wT,
                                          const double* __restrict__ Sxp,
                                          const double* __restrict__ part,
                                          float* __restrict__ sv_g,
                                          int* __restrict__ si_g,
                                          int* __restrict__ off_g,
                                          double* __restrict__ P_g,
                                          int* __restrict__ Mx_g,
                                          double* __restrict__ rv_g,
                                          int* __restrict__ ri_g,
                                          float* __restrict__ eb_g,
                                          double* __restrict__ hdrW,
                                          int* __restrict__ gmin_g) {
  int bid = blockIdx.x, tid = threadIdx.x;
  int lane = tid & 63, wid = tid >> 6;
  if (bid < OO) {
    int o = bid;
    __shared__ float sv[512];
    __shared__ int si[512];
    __shared__ int cnt[512];
    __shared__ int off[513];
    __shared__ double P[513];
    __shared__ int Mx[513];
    __shared__ double wsc[4];
    __shared__ int wmn[4];
    __shared__ unsigned long long wk[4];
    int i0 = 2 * tid, i1 = 2 * tid + 1;
    float w0 = wT[o * DD + i0], w1 = wT[o * DD + i1];
    cnt[i0] = 0; cnt[i1] = 0;
    __syncthreads();
    int q0 = min(511, max(0, (int)(w0 * 512.0f)));
    int q1 = min(511, max(0, (int)(w1 * 512.0f)));
    int sl0 = atomicAdd(&cnt[q0], 1);
    int sl1 = atomicAdd(&cnt[q1], 1);
    __syncthreads();
    {
      int e0 = cnt[i0], e1 = cnt[i1];
      int s = e0 + e1, v = s;
      for (int d = 1; d < 64; d <<= 1) {
        int u = __shfl_up(v, d);
        if (lane >= d) v += u;
      }
      if (lane == 63) wmn[wid] = v;
      __syncthreads();
      int wp = 0;
      for (int u = 0; u < wid; ++u) wp += wmn[u];
      int ex = wp + (v - s);
      off[i0] = ex; off[i1] = ex + e0;
      if (tid == 255) off[512] = ex + s;
      __syncthreads();
    }
    sv[off[q0] + sl0] = w0; si[off[q0] + sl0] = i0;
    sv[off[q1] + sl1] = w1; si[off[q1] + sl1] = i1;
    __syncthreads();
    for (int q = tid; q < 512; q += 256) {
      int s = off[q], e = off[q + 1];
      for (int i = s + 1; i < e; ++i) {
        int ki = si[i]; float kv = sv[i]; int j = i - 1;
        while (j >= s && si[j] > ki) { si[j + 1] = si[j]; sv[j + 1] = sv[j]; --j; }
        si[j + 1] = ki; sv[j + 1] = kv;
      }
    }
    __syncthreads();
    {
      double e0 = (double)sv[i0], e1 = (double)sv[i1];
      int m0 = si[i0], m1 = si[i1];
      double s = e0 + e1; int mm = min(m0, m1);
      double vs = s; int vm = mm;
      for (int d = 1; d < 64; d <<= 1) {
        double us = __shfl_up(vs, d);
        int um = __shfl_up(vm, d);
        if (lane >= d) { vs += us; vm = min(vm, um); }
      }
      double exs = __shfl_up(vs, 1);
      int exm = __shfl_up(vm, 1);
      if (lane == 0) { exs = 0.0; exm = 0x7fffffff; }
      if (lane == 63) { wsc[wid] = vs; wmn[wid] = vm; }
      __syncthreads();
      double wp = 0.0; int wm = 0x7fffffff;
      for (int u = 0; u < wid; ++u) { wp += wsc[u]; wm = min(wm, wmn[u]); }
      double EX = wp + exs; int EXM = min(wm, exm);
      P[i0] = EX; P[i1] = EX + e0;
      Mx[i0] = EXM; Mx[i1] = min(EXM, m0);
      if (tid == 255) { P[512] = EX + s; Mx[512] = min(EXM, mm); }
      __syncthreads();
    }
    {
      unsigned long long k0 = ((unsigned long long)__float_as_uint(sv[i0]) << 32) | (unsigned)si[i0];
      unsigned long long k1 = ((unsigned long long)__float_as_uint(sv[i1]) << 32) | (unsigned)si[i1];
      unsigned long long kk = k0 < k1 ? k0 : k1;
      for (int d = 32; d > 0; d >>= 1) {
        unsigned long long u = __shfl_down(kk, d);
        kk = u < kk ? u : kk;
      }
      if (lane == 0) wk[wid] = kk;
      __syncthreads();
      if (tid == 0) {
        unsigned long long g = wk[0];
        for (int u = 1; u < 4; ++u) g = wk[u] < g ? wk[u] : g;
        gmin_g[o] = (int)(g & 0xffffffffull);
      }
    }
    for (int i = tid; i < 512; i += 256) {
      sv_g[o * 512 + i] = sv[i];
      si_g[o * 512 + i] = si[i];
    }
    for (int i = tid; i < 513; i += 256) {
      off_g[o * 513 + i] = off[i];
      P_g[o * 513 + i] = P[i];
      Mx_g[o * 513 + i] = Mx[i];
    }
    if (tid == 0) { hdrW[o * 2 + 0] = 512.0 - P[512]; hdrW[o * 2 + 1] = P[512]; }
  } else {
    int o = bid - OO;
    __shared__ double rl[512];
    __shared__ int cnt2[512];
    __shared__ int roff[513];
    __shared__ double rv[512];
    __shared__ int ri[512];
    __shared__ float eb[512];
    __shared__ double wred[8];
    __shared__ int wint[4];
    int i0 = 2 * tid, i1 = 2 * tid + 1;
    {
      double sx0 = 0.0, sx1 = 0.0, a0 = 0.0, a1 = 0.0;
#pragma unroll
      for (int s = 0; s < 8; ++s) {
        sx0 += Sxp[s * DD + i0];
        sx1 += Sxp[s * DD + i1];
        a0 += part[(s * DD + i0) * OO + o];
        a1 += part[(s * DD + i1) * OO + o];
      }
      rl[i0] = 1.0 - (1024.0 - a0) / sx0;
      rl[i1] = 1.0 - (1024.0 - a1) / sx1;
    }
    double mn = fmin(rl[i0], rl[i1]), mx = fmax(rl[i0], rl[i1]);
    for (int d = 32; d > 0; d >>= 1) {
      mn = fmin(mn, __shfl_down(mn, d));
      mx = fmax(mx, __shfl_down(mx, d));
    }
    if (lane == 0) { wred[wid] = mn; wred[4 + wid] = mx; }
    cnt2[i0] = 0; cnt2[i1] = 0;
    __syncthreads();
    double rmin = fmin(fmin(wred[0], wred[1]), fmin(wred[2], wred[3]));
    double rmax = fmax(fmax(wred[4], wred[5]), fmax(wred[6], wred[7]));
    double range = rmax - rmin;
    double scale = (range > 0.0) ? (512.0 / range) : 0.0;
    double bw = range * (1.0 / 512.0);
    double base = rmin - range * 1e-9;  // margin absorbs f64 quantizer rounding
    int q0 = min(511, max(0, (int)((rl[i0] - rmin) * scale)));
    int q1 = min(511, max(0, (int)((rl[i1] - rmin) * scale)));
    int sl0 = atomicAdd(&cnt2[q0], 1);
    int sl1 = atomicAdd(&cnt2[q1], 1);
    __syncthreads();
    {
      int e0 = cnt2[i0], e1 = cnt2[i1];
      int s = e0 + e1, v = s;
      for (int d = 1; d < 64; d <<= 1) {
        int u = __shfl_up(v, d);
        if (lane >= d) v += u;
      }
      if (lane == 63) wint[wid] = v;
      __syncthreads();
      int wp = 0;
      for (int u = 0; u < wid; ++u) wp += wint[u];
      int ex = wp + (v - s);
      roff[i0] = ex; roff[i1] = ex + e0;
      if (tid == 255) roff[512] = ex + s;
      __syncthreads();
    }
    {
      int p0 = roff[q0] + sl0, p1 = roff[q1] + sl1;
      rv[p0] = rl[i0]; ri[p0] = i0;
      eb[p0] = __double2float_rd(base + (double)q0 * bw);  // <= true bound
      rv[p1] = rl[i1]; ri[p1] = i1;
      eb[p1] = __double2float_rd(base + (double)q1 * bw);
    }
    __syncthreads();
    for (int i = tid; i < 512; i += 256) {
      rv_g[o * 512 + i] = rv[i];
      ri_g[o * 512 + i] = ri[i];
      eb_g[o * 512 + i] = eb[i];
    }
  }
}

// ===========================================================================
// kC: per (b,o) queries.
// ===========================================================================
__global__ __launch_bounds__(256) void kC(
    const float* __restrict__ xT, const float* __restrict__ wT,
    const float* __restrict__ tT, const float* __restrict__ sv_g,
    const int* __restrict__ si_g, const int* __restrict__ off_g,
    const double* __restrict__ P_g, const int* __restrict__ Mx_g,
    const double* __restrict__ rv_g, const int* __restrict__ ri_g,
    const float* __restrict__ eb_g, const double* __restrict__ hdrW,
    const int* __restrict__ gmin_g, float* __restrict__ out) {
  int o = blockIdx.x, tid = threadIdx.x;
  int b = blockIdx.y * 256 + tid;
  __shared__ float sv[512];
  __shared__ int si[512];
  __shared__ int off[513];
  __shared__ double P[513];
  __shared__ int Mx[513];
  __shared__ double rv[512];
  __shared__ int ri[512];
  __shared__ float eb[512];
  __shared__ float wl[512];
  for (int i = tid; i < 512; i += 256) {
    sv[i] = sv_g[o * 512 + i];
    si[i] = si_g[o * 512 + i];
    rv[i] = rv_g[o * 512 + i];
    ri[i] = ri_g[o * 512 + i];
    eb[i] = eb_g[o * 512 + i];
    wl[i] = wT[o * DD + i];
  }
  for (int i = tid; i < 513; i += 256) {
    off[i] = off_g[o * 513 + i];
    P[i] = P_g[o * 513 + i];
    Mx[i] = Mx_g[o * 513 + i];
  }
  __syncthreads();
  double Sw = hdrW[o * 2 + 0], Wtot = hdrW[o * 2 + 1];
  float c = tT[o * BB + b];
  // Q1: prefix count/sum of {w <= c}
  int j = min(511, max(0, (int)(c * 512.0f)));
  int s0 = off[j], e0 = off[j + 1];
  double pre = P[s0];
  int k = s0;
  for (int i = s0; i < e0; ++i) {
    float wv = sv[i];
    if (wv <= c) { pre += (double)wv; ++k; }
  }
  double smax = (Wtot - pre) + (double)c * (double)k;
  double relw = 1.0 - (512.0 - smax) / Sw;
  // Q2: min original index with w <= relw. Scan buckets j2 AND j2+1 (the
  // f32 element-quantizer can round an eligible w into bucket j2+1).
  int j2 = min(511, max(0, (int)(relw * 512.0)));
  int s2 = off[j2], e2 = off[min(512, j2 + 2)];
  int iw = Mx[s2];
  for (int i = s2; i < e2; ++i)
    if ((double)sv[i] <= relw) iw = min(iw, si[i]);
  if (iw == 0x7fffffff) iw = gmin_g[o];
  // RX: argmin_d max(x, relx), ascending-bucket scan with safe break bound
  float x0 = xT[ri[0] * BB + b], x1 = xT[ri[1] * BB + b];
  float x2 = xT[ri[2] * BB + b], x3 = xT[ri[3] * BB + b];
  float x4 = xT[ri[4] * BB + b], x5 = xT[ri[5] * BB + b];
  float x6 = xT[ri[6] * BB + b], x7 = xT[ri[7] * BB + b];
  double best = 1e300;
  int bix = 0x7fffffff;
  float bestx = 0.0f;
  for (int i = 0; i < 512; ++i) {
    if ((double)eb[i] > best) break;
    int dj = ri[i];
    float xv;
    if (i < 8) {
      xv = (i == 0) ? x0 : (i == 1) ? x1 : (i == 2) ? x2 : (i == 3) ? x3
         : (i == 4) ? x4 : (i == 5) ? x5 : (i == 6) ? x6 : x7;
    } else {
      xv = xT[dj * BB + b];
    }
    double v = fmax((double)xv, rv[i]);
    if (v < best || (v == best && dj < bix)) { best = v; bix = dj; bestx = xv; }
  }
  float ox = fmaxf(bestx, wl[bix]);
  float ow = fmaxf(xT[iw * BB + b], wl[iw]);
  out[b * OO + o] = ox;
  out[BB * OO + b * OO + o] = ow;
}

// ===========================================================================
extern "C" void kernel_launch(void* const* d_in, const int* in_sizes, int n_in,
                              void* d_out, int out_size, void* d_ws,
                              size_t ws_size, hipStream_t stream) {
  const float* x = (const float*)d_in[0];  // (B,D)
  const float* w = (const float*)d_in[1];  // (D,O)
  const float* t = (const float*)d_in[2];  // (B,O)
  float* out = (float*)d_out;
  char* ws = (char*)d_ws;

  size_t off = 0;
  float* xT    = (float*)(ws + off);  off += (size_t)DD * BB * 4;       // 2 MB
  float* tT    = (float*)(ws + off);  off += (size_t)OO * BB * 4;       // 1 MB
  float* wT    = (float*)(ws + off);  off += (size_t)OO * DD * 4;       // .5 MB
  double* Sxp  = (double*)(ws + off); off += (size_t)8 * DD * 8;        // 32 KB
  double* part = (double*)(ws + off); off += (size_t)8 * DD * OO * 8;   // 8 MB
  float* sv_g  = (float*)(ws + off);  off += (size_t)OO * 512 * 4;
  int* si_g    = (int*)(ws + off);    off += (size_t)OO * 512 * 4;
  int* off_g   = (int*)(ws + off);    off += (size_t)OO * 513 * 4;
  double* P_g  = (double*)(ws + off); off += (size_t)OO * 513 * 8;
  int* Mx_g    = (int*)(ws + off);    off += (size_t)OO * 513 * 4;
  double* rv_g = (double*)(ws + off); off += (size_t)OO * 512 * 8;
  int* ri_g    = (int*)(ws + off);    off += (size_t)OO * 512 * 4;
  float* eb_g  = (float*)(ws + off);  off += (size_t)OO * 512 * 4;
  double* hdrW = (double*)(ws + off); off += (size_t)OO * 2 * 8;
  int* gmin_g  = (int*)(ws + off);    off += (size_t)OO * 4;

  kA<<<1424, 256, 0, stream>>>(x, w, t, xT, tT, wT, Sxp, part);
  kB<<<2 * OO, 256, 0, stream>>>(wT, Sxp, part, sv_g, si_g, off_g, P_g, Mx_g,
                                 rv_g, ri_g, eb_g, hdrW, gmin_g);
  kC<<<dim3(OO, BB / 256), 256, 0, stream>>>(xT, wT, tT, sv_g, si_g, off_g,
                                             P_g, Mx_g, rv_g, ri_g, eb_g,
                                             hdrW, gmin_g, out);
}